// Round 9
// baseline (49.400 us; speedup 1.0000x reference)
//
#include <hip/hip_runtime.h>
#include <math.h>

#define NPTS 262144
#define B_KB 4.71238898038469f      /* 1.5*pi */
#define B_KB2 22.2066099025f        /* B_KB^2 */
#define PI_F 3.14159265358979f
#define INV_2PI 0.15915494309f      /* 1/(2*pi) */
#define TWO_PI_OVER_N 0.01227184630309f /* 2*pi/512 */
#define NCOL 520                    /* padded row stride: 512 + 8 dup cols */

#define CHROWS 16                   /* rows per LDS chunk */
#define NCHUNK 32                   /* 512 / 16 */
#define NPART 8                     /* point partitions */
#define PTS_PER_PART (NPTS / NPART) /* 32768 */
#define LSTRIDE 521                 /* LDS chunk stride (bank spread) */
#define MAXLIST 2048                /* compacted work-list cap (mean 1472) */

__device__ __forceinline__ float i0f_dev(float x) {
    float ax = fabsf(x);
    if (ax < 3.75f) {
        float t = ax / 3.75f; t *= t;
        return 1.0f + t*(3.5156229f + t*(3.0899424f + t*(1.2067492f +
               t*(0.2659732f + t*(0.0360768f + t*0.0045813f)))));
    } else {
        float t = 3.75f / ax;
        float p = 0.39894228f + t*(0.01328592f + t*(0.00225319f + t*(-0.00157565f +
                  t*(0.00916281f + t*(-0.02057706f + t*(0.02635537f +
                  t*(-0.01647633f + t*0.00392377f)))))));
        return expf(ax) * p / sqrtf(ax);
    }
}

// Kaiser-Bessel window via raw v_exp/v_rcp: sinh(B*a)/(pi*a), a=sqrt(16-t^2)
__device__ __forceinline__ float phi_win(float t) {
    float s = 16.0f - t * t;
    if (s <= 0.0f) return 0.0f;
    float a = sqrtf(s);
    float ez = __expf(B_KB * a);
    return (ez - __builtin_amdgcn_rcpf(ez)) * INV_2PI * __builtin_amdgcn_rcpf(a);
}

// ---- Fused deconvolution + row FFT (rows with nonzero spectrum only). ----
__global__ void rowfft_build(const float* __restrict__ fr,
                             const float* __restrict__ fi,
                             float2* __restrict__ g) {
    __shared__ float2 buf[512];
    int r = blockIdx.x;
    int i1 = (r < 128) ? r : r + 256;
    int k1 = (r < 128) ? r : r - 256;
    int tid = threadIdx.x;                 // 256 threads
    float a1 = TWO_PI_OVER_N * (float)k1;
    float ph1 = i0f_dev(4.0f * sqrtf(B_KB2 - a1 * a1));

    int k2 = tid - 128;                    // [-128, 128)
    int i2 = k2 & 511;
    float a2 = TWO_PI_OVER_N * (float)k2;
    float ph2 = i0f_dev(4.0f * sqrtf(B_KB2 - a2 * a2));
    float inv = 1.0f / (ph1 * ph2);
    if ((i1 + i2) & 1) inv = -inv;
    int fidx = (k1 + 128) * 256 + (k2 + 128);
    float2 v = make_float2(fr[fidx] * inv, fi[fidx] * inv);

    buf[tid] = make_float2(0.0f, 0.0f);
    buf[tid + 256] = make_float2(0.0f, 0.0f);
    __syncthreads();
    int ri = (int)(__brev((unsigned)i2) >> 23);   // 9-bit reversal
    buf[ri] = v;
    __syncthreads();

    #pragma unroll
    for (int s = 1; s <= 9; ++s) {
        int half = 1 << (s - 1);
        int pos = tid & (half - 1);
        int j1 = ((tid >> (s - 1)) << s) | pos;
        float ang = -PI_F * (float)pos / (float)half;
        float sw, cw;
        __sincosf(ang, &sw, &cw);
        float2 u = buf[j1];
        float2 w = buf[j1 + half];
        float wr = cw * w.x - sw * w.y;
        float wi = cw * w.y + sw * w.x;
        buf[j1]        = make_float2(u.x + wr, u.y + wi);
        buf[j1 + half] = make_float2(u.x - wr, u.y - wi);
        __syncthreads();
    }
    long base = (long)i1 * NCOL;
    for (int j = tid; j < 512; j += 256) g[base + j] = buf[j];
    if (tid < 8) g[base + 512 + tid] = buf[tid];   // duplicate cols for padding
}

// ---- Column FFT over the 256 nonzero rows only; REAL part to f32 grid. ----
__global__ void colfft_real(const float2* __restrict__ g,
                            float* __restrict__ gre) {
    __shared__ float2 buf[512];
    int c = blockIdx.x;                    // 0..519
    int tid = threadIdx.x;                 // 256 threads
    buf[tid] = make_float2(0.0f, 0.0f);
    buf[tid + 256] = make_float2(0.0f, 0.0f);
    __syncthreads();
    int r = (tid < 128) ? tid : tid + 256;           // nonzero rows
    int rr = (int)(__brev((unsigned)r) >> 23);       // 9-bit reversal
    buf[rr] = g[(long)r * NCOL + c];
    __syncthreads();
    #pragma unroll
    for (int s = 1; s <= 9; ++s) {
        int half = 1 << (s - 1);
        int pos = tid & (half - 1);
        int j1 = ((tid >> (s - 1)) << s) | pos;
        float ang = -PI_F * (float)pos / (float)half;
        float sw, cw;
        __sincosf(ang, &sw, &cw);
        float2 u = buf[j1];
        float2 w = buf[j1 + half];
        float wr = cw * w.x - sw * w.y;
        float wi = cw * w.y + sw * w.x;
        buf[j1]        = make_float2(u.x + wr, u.y + wi);
        buf[j1 + half] = make_float2(u.x - wr, u.y - wi);
        __syncthreads();
    }
    for (int j = tid; j < 512; j += 256) gre[(long)j * NCOL + c] = buf[j].x;
}

// ---- d_out zero-init (required: ws/out poisoned, gather accumulates). ----
__global__ void zero_out(float* __restrict__ out) {
    out[blockIdx.x * 1024 + threadIdx.x] = 0.0f;
}

// ---- LDS-chunked gather: block = (row-chunk c, point-partition p).
// Stage 16 grid rows in LDS; ballot-compact the partition's points whose
// window touches the chunk; gather from LDS; atomicAdd partial to out.
// Each point gets <=2 partials (2-term float add is commutative ->
// deterministic). ----
__global__ __launch_bounds__(1024)
void gather_chunks(const float2* __restrict__ x,
                   const float* __restrict__ gre,
                   float* __restrict__ out) {
    __shared__ float chunk[CHROWS][LSTRIDE];
    __shared__ float2 lx[MAXLIST];
    __shared__ int lm[MAXLIST];
    __shared__ int lcount;
    int tid = threadIdx.x;
    int c = blockIdx.x >> 3;               // chunk index 0..31
    int p = blockIdx.x & 7;                // partition 0..7
    if (tid == 0) lcount = 0;

    // stage rows [16c, 16c+16) of gre (contiguous, coalesced)
    for (int r = 0; r < CHROWS; ++r) {
        for (int j = tid; j < NCOL; j += 1024)
            chunk[r][j] = gre[(long)(c * CHROWS + r) * NCOL + j];
    }
    __syncthreads();

    // scan + ballot-compact active points
    int lane = tid & 63;
    int mbase = p * PTS_PER_PART;
    for (int k = 0; k < PTS_PER_PART / 1024; ++k) {
        int m = mbase + k * 1024 + tid;
        float2 xv = x[m];
        int b1 = (int)ceilf(xv.x * 512.0f) - 4;
        int r0 = (b1 + 768) & 511;
        bool act = ((r0 >> 4) == c) || ((((r0 + 7) & 511) >> 4) == c);
        unsigned long long mask = __ballot(act);
        if (mask) {
            int leader = (int)__ffsll((unsigned long long)mask) - 1;
            int base = 0;
            if (lane == leader) base = atomicAdd(&lcount, (int)__popcll(mask));
            base = __shfl(base, leader);
            if (act) {
                int slot = base + (int)__popcll(mask & ((1ULL << lane) - 1ULL));
                if (slot < MAXLIST) { lx[slot] = xv; lm[slot] = m; }
            }
        }
    }
    __syncthreads();

    int n = lcount; if (n > MAXLIST) n = MAXLIST;
    for (int i = tid; i < n; i += 1024) {
        float2 xv = lx[i];
        int m = lm[i];
        float v1 = xv.x * 512.0f, v2 = xv.y * 512.0f;
        float c1 = ceilf(v1), c2 = ceilf(v2);
        int b1 = (int)c1 - 4, b2 = (int)c2 - 4;
        float f1 = c1 - v1, f2 = c2 - v2;
        float phi2[8];
        #pragma unroll
        for (int w = 0; w < 8; ++w) phi2[w] = phi_win(4.0f - (float)w - f2);
        int r0 = (b1 + 768) & 511;
        int cb = (b2 + 768) & 511;
        float acc = 0.0f;
        #pragma unroll
        for (int w = 0; w < 8; ++w) {
            int row = (r0 + w) & 511;
            if ((row >> 4) != c) continue;
            int rl = row & 15;
            float p1 = phi_win(4.0f - (float)w - f1);
            float rs = 0.0f;
            #pragma unroll
            for (int j = 0; j < 8; ++j) rs += phi2[j] * chunk[rl][cb + j];
            acc += p1 * rs;
        }
        atomicAdd(&out[m], acc);
    }
}

// ================== fallback path (complex-capable, f32) ==================
__global__ void build_ghat(const float* __restrict__ fr,
                           const float* __restrict__ fi,
                           float2* __restrict__ g, int ldg) {
    int idx = blockIdx.x * 256 + threadIdx.x;
    int i1 = idx >> 9;
    int i2 = idx & 511;
    float2 val = make_float2(0.0f, 0.0f);
    int k1 = 0, k2 = 0;
    bool ok = true;
    if (i1 < 128) k1 = i1; else if (i1 >= 384) k1 = i1 - 512; else ok = false;
    if (ok) { if (i2 < 128) k2 = i2; else if (i2 >= 384) k2 = i2 - 512; else ok = false; }
    if (ok) {
        float a1 = TWO_PI_OVER_N * (float)k1;
        float a2 = TWO_PI_OVER_N * (float)k2;
        float ph1 = i0f_dev(4.0f * sqrtf(B_KB2 - a1*a1));
        float ph2 = i0f_dev(4.0f * sqrtf(B_KB2 - a2*a2));
        float inv = 1.0f / (ph1 * ph2);
        if ((i1 + i2) & 1) inv = -inv;
        int fidx = (k1 + 128) * 256 + (k2 + 128);
        val.x = fr[fidx] * inv;
        val.y = fi[fidx] * inv;
    }
    g[i1 * ldg + i2] = val;
}

__global__ void fft_lines(float2* __restrict__ g, int line_stride,
                          int elem_stride, int ndup) {
    __shared__ float2 buf[512];
    int line = blockIdx.x;
    int tid = threadIdx.x;
    long base = (long)line * line_stride;
    for (int j = tid; j < 512; j += 256) {
        int rj = (int)(__brev((unsigned)j) >> 23);
        buf[rj] = g[base + (long)j * elem_stride];
    }
    __syncthreads();
    #pragma unroll
    for (int s = 1; s <= 9; ++s) {
        int half = 1 << (s - 1);
        int pos = tid & (half - 1);
        int i1 = ((tid >> (s - 1)) << s) | pos;
        float ang = -PI_F * (float)pos / (float)half;
        float sw, cw;
        __sincosf(ang, &sw, &cw);
        float2 u = buf[i1];
        float2 v = buf[i1 + half];
        float wr = cw * v.x - sw * v.y;
        float wi = cw * v.y + sw * v.x;
        buf[i1]        = make_float2(u.x + wr, u.y + wi);
        buf[i1 + half] = make_float2(u.x - wr, u.y - wi);
        __syncthreads();
    }
    for (int j = tid; j < 512; j += 256) g[base + (long)j * elem_stride] = buf[j];
    for (int j = tid; j < ndup; j += 256) g[base + 512 + j] = buf[j];
}

template<int COMPLEX>
__global__ __launch_bounds__(256, 4)
void gather_pad(const float2* __restrict__ x,
                const float2* __restrict__ g,
                float* __restrict__ out) {
    int m = blockIdx.x * 256 + threadIdx.x;
    float2 xv = x[m];
    float v1 = xv.x * 512.0f;
    float v2 = xv.y * 512.0f;
    float c1 = ceilf(v1), c2 = ceilf(v2);
    int b1 = (int)c1 - 4, b2 = (int)c2 - 4;
    float f1 = c1 - v1, f2 = c2 - v2;

    float phi1[8], phi2[8];
    int rowb[8];
    #pragma unroll
    for (int w = 0; w < 8; ++w) {
        phi1[w] = phi_win(4.0f - (float)w - f1);
        phi2[w] = phi_win(4.0f - (float)w - f2);
        rowb[w] = ((b1 + w + 768) & 511) * NCOL;
    }
    int cb = (b2 + 768) & 511;

    float accx = 0.0f, accy = 0.0f;
    #pragma unroll
    for (int w1 = 0; w1 < 8; ++w1) {
        const float4* p = reinterpret_cast<const float4*>(g + rowb[w1] + cb);
        float4 va = p[0], vb = p[1], vc = p[2], vd = p[3];
        float p1 = phi1[w1];
        accx += p1 * (phi2[0]*va.x + phi2[1]*va.z + phi2[2]*vb.x + phi2[3]*vb.z +
                      phi2[4]*vc.x + phi2[5]*vc.z + phi2[6]*vd.x + phi2[7]*vd.z);
        if (COMPLEX)
            accy += p1 * (phi2[0]*va.y + phi2[1]*va.w + phi2[2]*vb.y + phi2[3]*vb.w +
                          phi2[4]*vc.y + phi2[5]*vc.w + phi2[6]*vd.y + phi2[7]*vd.w);
    }
    if (COMPLEX) ((float2*)out)[m] = make_float2(accx, accy);
    else out[m] = accx;
}

extern "C" void kernel_launch(void* const* d_in, const int* in_sizes, int n_in,
                              void* d_out, int out_size, void* d_ws, size_t ws_size,
                              hipStream_t stream) {
    const float* x  = (const float*)d_in[0];
    const float* fr = (const float*)d_in[1];
    const float* fi = (const float*)d_in[2];
    int cplx = (out_size >= 2 * NPTS) ? 1 : 0;

    size_t g_bytes   = (size_t)512 * NCOL * sizeof(float2);  // 2,129,920
    size_t gre_bytes = (size_t)512 * NCOL * sizeof(float);   // 1,064,960
    char* ws = (char*)d_ws;
    float2* g   = (float2*)ws;
    float*  gre = (float*)(ws + g_bytes);
    size_t need = g_bytes + gre_bytes;

    if (!cplx && ws_size >= need) {
        // Fast path: R5 front-end + LDS-chunked compacted gather.
        zero_out<<<NPTS / 1024, 1024, 0, stream>>>((float*)d_out);
        rowfft_build<<<256, 256, 0, stream>>>(fr, fi, g);
        colfft_real<<<NCOL, 256, 0, stream>>>(g, gre);
        gather_chunks<<<NCHUNK * NPART, 1024, 0, stream>>>((const float2*)x, gre,
                                                           (float*)d_out);
    } else if (ws_size >= g_bytes) {
        build_ghat<<<1024, 256, 0, stream>>>(fr, fi, g, NCOL);
        fft_lines<<<512, 256, 0, stream>>>(g, NCOL, 1, 8);
        fft_lines<<<NCOL, 256, 0, stream>>>(g, 1, NCOL, 0);
        if (cplx)
            gather_pad<1><<<1024, 256, 0, stream>>>((const float2*)x, g, (float*)d_out);
        else
            gather_pad<0><<<1024, 256, 0, stream>>>((const float2*)x, g, (float*)d_out);
    } else {
        build_ghat<<<1024, 256, 0, stream>>>(fr, fi, g, 512);
        fft_lines<<<512, 256, 0, stream>>>(g, 512, 1, 0);
        fft_lines<<<512, 256, 0, stream>>>(g, 1, 512, 0);
        if (cplx)
            gather_pad<1><<<1024, 256, 0, stream>>>((const float2*)x, g, (float*)d_out);
        else
            gather_pad<0><<<1024, 256, 0, stream>>>((const float2*)x, g, (float*)d_out);
    }
}

// Round 10
// 30.231 us; speedup vs baseline: 1.6341x; 1.6341x over previous
//
#include <hip/hip_runtime.h>
#include <math.h>

#define NPTS 262144
#define B_KB 4.71238898038469f      /* 1.5*pi */
#define B_KB2 22.2066099025f        /* B_KB^2 */
#define PI_F 3.14159265358979f
#define INV_2PI 0.15915494309f      /* 1/(2*pi) */
#define TWO_PI_OVER_N 0.01227184630309f /* 2*pi/512 */
#define NCOL 520                    /* padded row stride: 512 + 8 dup cols */

__device__ __forceinline__ float i0f_dev(float x) {
    float ax = fabsf(x);
    if (ax < 3.75f) {
        float t = ax / 3.75f; t *= t;
        return 1.0f + t*(3.5156229f + t*(3.0899424f + t*(1.2067492f +
               t*(0.2659732f + t*(0.0360768f + t*0.0045813f)))));
    } else {
        float t = 3.75f / ax;
        float p = 0.39894228f + t*(0.01328592f + t*(0.00225319f + t*(-0.00157565f +
                  t*(0.00916281f + t*(-0.02057706f + t*(0.02635537f +
                  t*(-0.01647633f + t*0.00392377f)))))));
        return expf(ax) * p / sqrtf(ax);
    }
}

// Kaiser-Bessel window via raw v_exp/v_rcp: sinh(B*a)/(pi*a), a=sqrt(16-t^2)
__device__ __forceinline__ float phi_win(float t) {
    float s = 16.0f - t * t;
    if (s <= 0.0f) return 0.0f;
    float a = sqrtf(s);
    float ez = __expf(B_KB * a);
    return (ez - __builtin_amdgcn_rcpf(ez)) * INV_2PI * __builtin_amdgcn_rcpf(a);
}

// ---- Fused deconvolution + row FFT (rows with nonzero spectrum only). ----
__global__ void rowfft_build(const float* __restrict__ fr,
                             const float* __restrict__ fi,
                             float2* __restrict__ g) {
    __shared__ float2 buf[512];
    int r = blockIdx.x;
    int i1 = (r < 128) ? r : r + 256;
    int k1 = (r < 128) ? r : r - 256;
    int tid = threadIdx.x;                 // 256 threads
    float a1 = TWO_PI_OVER_N * (float)k1;
    float ph1 = i0f_dev(4.0f * sqrtf(B_KB2 - a1 * a1));

    int k2 = tid - 128;                    // [-128, 128)
    int i2 = k2 & 511;
    float a2 = TWO_PI_OVER_N * (float)k2;
    float ph2 = i0f_dev(4.0f * sqrtf(B_KB2 - a2 * a2));
    float inv = 1.0f / (ph1 * ph2);
    if ((i1 + i2) & 1) inv = -inv;
    int fidx = (k1 + 128) * 256 + (k2 + 128);
    float2 v = make_float2(fr[fidx] * inv, fi[fidx] * inv);

    buf[tid] = make_float2(0.0f, 0.0f);
    buf[tid + 256] = make_float2(0.0f, 0.0f);
    __syncthreads();
    int ri = (int)(__brev((unsigned)i2) >> 23);   // 9-bit reversal
    buf[ri] = v;
    __syncthreads();

    #pragma unroll
    for (int s = 1; s <= 9; ++s) {
        int half = 1 << (s - 1);
        int pos = tid & (half - 1);
        int j1 = ((tid >> (s - 1)) << s) | pos;
        float ang = -PI_F * (float)pos / (float)half;
        float sw, cw;
        __sincosf(ang, &sw, &cw);
        float2 u = buf[j1];
        float2 w = buf[j1 + half];
        float wr = cw * w.x - sw * w.y;
        float wi = cw * w.y + sw * w.x;
        buf[j1]        = make_float2(u.x + wr, u.y + wi);
        buf[j1 + half] = make_float2(u.x - wr, u.y - wi);
        __syncthreads();
    }
    long base = (long)i1 * NCOL;
    for (int j = tid; j < 512; j += 256) g[base + j] = buf[j];
    if (tid < 8) g[base + 512 + tid] = buf[tid];   // duplicate cols for padding
}

// ---- Column FFT over the 256 nonzero rows only; REAL part to f32 grid. ----
__global__ void colfft_real(const float2* __restrict__ g,
                            float* __restrict__ gre) {
    __shared__ float2 buf[512];
    int c = blockIdx.x;                    // 0..519
    int tid = threadIdx.x;                 // 256 threads
    buf[tid] = make_float2(0.0f, 0.0f);
    buf[tid + 256] = make_float2(0.0f, 0.0f);
    __syncthreads();
    int r = (tid < 128) ? tid : tid + 256;           // nonzero rows
    int rr = (int)(__brev((unsigned)r) >> 23);       // 9-bit reversal
    buf[rr] = g[(long)r * NCOL + c];
    __syncthreads();
    #pragma unroll
    for (int s = 1; s <= 9; ++s) {
        int half = 1 << (s - 1);
        int pos = tid & (half - 1);
        int j1 = ((tid >> (s - 1)) << s) | pos;
        float ang = -PI_F * (float)pos / (float)half;
        float sw, cw;
        __sincosf(ang, &sw, &cw);
        float2 u = buf[j1];
        float2 w = buf[j1 + half];
        float wr = cw * w.x - sw * w.y;
        float wi = cw * w.y + sw * w.x;
        buf[j1]        = make_float2(u.x + wr, u.y + wi);
        buf[j1 + half] = make_float2(u.x - wr, u.y - wi);
        __syncthreads();
    }
    for (int j = tid; j < 512; j += 256) gre[(long)j * NCOL + c] = buf[j].x;
}

// ---- Split gather: 2 threads per point (lanes 2k, 2k+1), 4 window rows
// each (8 vmem insts/thread). Doubles resident waves (2048 blocks -> 32
// waves/CU) for latency hiding; halves per-thread VALU. Pair-combined via
// shfl_xor; even lane stores (contiguous). ----
__global__ __launch_bounds__(256)
void gather_split(const float2* __restrict__ x,
                  const float* __restrict__ gre,
                  float* __restrict__ out) {
    int t = blockIdx.x * 256 + threadIdx.x;   // 0 .. 2*NPTS-1
    int m = t >> 1;
    int h = t & 1;
    float2 xv = x[m];
    float v1 = xv.x * 512.0f;
    float v2 = xv.y * 512.0f;
    float c1 = ceilf(v1), c2 = ceilf(v2);
    int b1 = (int)c1 - 4, b2 = (int)c2 - 4;
    float f1 = c1 - v1, f2 = c2 - v2;

    float phi2[8];
    #pragma unroll
    for (int j = 0; j < 8; ++j) phi2[j] = phi_win(4.0f - (float)j - f2);
    int cb = (b2 + 768) & 511;
    int w0 = h * 4;

    int rowb[4];
    #pragma unroll
    for (int w = 0; w < 4; ++w)
        rowb[w] = ((b1 + w0 + w + 768) & 511) * NCOL;

    float4 rA[4], rB[4];
    #pragma unroll
    for (int w = 0; w < 4; ++w) {
        const float4* p = reinterpret_cast<const float4*>(gre + rowb[w] + cb);
        rA[w] = p[0];
        rB[w] = p[1];
    }
    float acc = 0.0f;
    #pragma unroll
    for (int w = 0; w < 4; ++w) {
        float p1 = phi_win(4.0f - (float)(w0 + w) - f1);
        acc += p1 * (phi2[0]*rA[w].x + phi2[1]*rA[w].y +
                     phi2[2]*rA[w].z + phi2[3]*rA[w].w +
                     phi2[4]*rB[w].x + phi2[5]*rB[w].y +
                     phi2[6]*rB[w].z + phi2[7]*rB[w].w);
    }
    acc += __shfl_xor(acc, 1);
    if (h == 0) out[m] = acc;
}

// ================== fallback path (complex-capable, f32) ==================
__global__ void build_ghat(const float* __restrict__ fr,
                           const float* __restrict__ fi,
                           float2* __restrict__ g, int ldg) {
    int idx = blockIdx.x * 256 + threadIdx.x;
    int i1 = idx >> 9;
    int i2 = idx & 511;
    float2 val = make_float2(0.0f, 0.0f);
    int k1 = 0, k2 = 0;
    bool ok = true;
    if (i1 < 128) k1 = i1; else if (i1 >= 384) k1 = i1 - 512; else ok = false;
    if (ok) { if (i2 < 128) k2 = i2; else if (i2 >= 384) k2 = i2 - 512; else ok = false; }
    if (ok) {
        float a1 = TWO_PI_OVER_N * (float)k1;
        float a2 = TWO_PI_OVER_N * (float)k2;
        float ph1 = i0f_dev(4.0f * sqrtf(B_KB2 - a1*a1));
        float ph2 = i0f_dev(4.0f * sqrtf(B_KB2 - a2*a2));
        float inv = 1.0f / (ph1 * ph2);
        if ((i1 + i2) & 1) inv = -inv;
        int fidx = (k1 + 128) * 256 + (k2 + 128);
        val.x = fr[fidx] * inv;
        val.y = fi[fidx] * inv;
    }
    g[i1 * ldg + i2] = val;
}

__global__ void fft_lines(float2* __restrict__ g, int line_stride,
                          int elem_stride, int ndup) {
    __shared__ float2 buf[512];
    int line = blockIdx.x;
    int tid = threadIdx.x;
    long base = (long)line * line_stride;
    for (int j = tid; j < 512; j += 256) {
        int rj = (int)(__brev((unsigned)j) >> 23);
        buf[rj] = g[base + (long)j * elem_stride];
    }
    __syncthreads();
    #pragma unroll
    for (int s = 1; s <= 9; ++s) {
        int half = 1 << (s - 1);
        int pos = tid & (half - 1);
        int i1 = ((tid >> (s - 1)) << s) | pos;
        float ang = -PI_F * (float)pos / (float)half;
        float sw, cw;
        __sincosf(ang, &sw, &cw);
        float2 u = buf[i1];
        float2 v = buf[i1 + half];
        float wr = cw * v.x - sw * v.y;
        float wi = cw * v.y + sw * v.x;
        buf[i1]        = make_float2(u.x + wr, u.y + wi);
        buf[i1 + half] = make_float2(u.x - wr, u.y - wi);
        __syncthreads();
    }
    for (int j = tid; j < 512; j += 256) g[base + (long)j * elem_stride] = buf[j];
    for (int j = tid; j < ndup; j += 256) g[base + 512 + j] = buf[j];
}

template<int COMPLEX>
__global__ __launch_bounds__(256, 4)
void gather_pad(const float2* __restrict__ x,
                const float2* __restrict__ g,
                float* __restrict__ out) {
    int m = blockIdx.x * 256 + threadIdx.x;
    float2 xv = x[m];
    float v1 = xv.x * 512.0f;
    float v2 = xv.y * 512.0f;
    float c1 = ceilf(v1), c2 = ceilf(v2);
    int b1 = (int)c1 - 4, b2 = (int)c2 - 4;
    float f1 = c1 - v1, f2 = c2 - v2;

    float phi1[8], phi2[8];
    int rowb[8];
    #pragma unroll
    for (int w = 0; w < 8; ++w) {
        phi1[w] = phi_win(4.0f - (float)w - f1);
        phi2[w] = phi_win(4.0f - (float)w - f2);
        rowb[w] = ((b1 + w + 768) & 511) * NCOL;
    }
    int cb = (b2 + 768) & 511;

    float accx = 0.0f, accy = 0.0f;
    #pragma unroll
    for (int w1 = 0; w1 < 8; ++w1) {
        const float4* p = reinterpret_cast<const float4*>(g + rowb[w1] + cb);
        float4 va = p[0], vb = p[1], vc = p[2], vd = p[3];
        float p1 = phi1[w1];
        accx += p1 * (phi2[0]*va.x + phi2[1]*va.z + phi2[2]*vb.x + phi2[3]*vb.z +
                      phi2[4]*vc.x + phi2[5]*vc.z + phi2[6]*vd.x + phi2[7]*vd.z);
        if (COMPLEX)
            accy += p1 * (phi2[0]*va.y + phi2[1]*va.w + phi2[2]*vb.y + phi2[3]*vb.w +
                          phi2[4]*vc.y + phi2[5]*vc.w + phi2[6]*vd.y + phi2[7]*vd.w);
    }
    if (COMPLEX) ((float2*)out)[m] = make_float2(accx, accy);
    else out[m] = accx;
}

extern "C" void kernel_launch(void* const* d_in, const int* in_sizes, int n_in,
                              void* d_out, int out_size, void* d_ws, size_t ws_size,
                              hipStream_t stream) {
    const float* x  = (const float*)d_in[0];
    const float* fr = (const float*)d_in[1];
    const float* fi = (const float*)d_in[2];
    int cplx = (out_size >= 2 * NPTS) ? 1 : 0;

    size_t g_bytes   = (size_t)512 * NCOL * sizeof(float2);  // 2,129,920
    size_t gre_bytes = (size_t)512 * NCOL * sizeof(float);   // 1,064,960
    char* ws = (char*)d_ws;
    float2* g   = (float2*)ws;
    float*  gre = (float*)(ws + g_bytes);
    size_t need = g_bytes + gre_bytes;

    if (!cplx && ws_size >= need) {
        // Fast path: R5 front-end + 2-threads-per-point split gather
        // (32 waves/CU for latency hiding).
        rowfft_build<<<256, 256, 0, stream>>>(fr, fi, g);
        colfft_real<<<NCOL, 256, 0, stream>>>(g, gre);
        gather_split<<<2048, 256, 0, stream>>>((const float2*)x, gre, (float*)d_out);
    } else if (ws_size >= g_bytes) {
        build_ghat<<<1024, 256, 0, stream>>>(fr, fi, g, NCOL);
        fft_lines<<<512, 256, 0, stream>>>(g, NCOL, 1, 8);
        fft_lines<<<NCOL, 256, 0, stream>>>(g, 1, NCOL, 0);
        if (cplx)
            gather_pad<1><<<1024, 256, 0, stream>>>((const float2*)x, g, (float*)d_out);
        else
            gather_pad<0><<<1024, 256, 0, stream>>>((const float2*)x, g, (float*)d_out);
    } else {
        build_ghat<<<1024, 256, 0, stream>>>(fr, fi, g, 512);
        fft_lines<<<512, 256, 0, stream>>>(g, 512, 1, 0);
        fft_lines<<<512, 256, 0, stream>>>(g, 1, 512, 0);
        if (cplx)
            gather_pad<1><<<1024, 256, 0, stream>>>((const float2*)x, g, (float*)d_out);
        else
            gather_pad<0><<<1024, 256, 0, stream>>>((const float2*)x, g, (float*)d_out);
    }
}